// Round 12
// baseline (319.295 us; speedup 1.0000x reference)
//
#include <hip/hip_runtime.h>
#include <hip/hip_bf16.h>

typedef unsigned short u16;
typedef short bf8_t __attribute__((ext_vector_type(8)));
typedef float f32x4 __attribute__((ext_vector_type(4)));

__device__ inline u16 f2bf(float f) {
  unsigned u = __float_as_uint(f);
  u += 0x7FFFu + ((u >> 16) & 1u);
  return (u16)(u >> 16);
}
__device__ inline float bf2f(u16 h) { return __uint_as_float(((unsigned)h) << 16); }
__device__ inline float bflo(unsigned u) { return __uint_as_float(u << 16); }
__device__ inline float bfhi(unsigned u) { return __uint_as_float(u & 0xffff0000u); }

// ---------------- count (XCD-team filtered) + weight transposes ----------------
__global__ void prep_kernel(const int* __restrict__ ei, int E, int N, int N8,
                            int* __restrict__ counts,
                            const float* __restrict__ W1, const float* __restrict__ W2,
                            u16* __restrict__ W1T, u16* __restrict__ W2T, int teamBlocks) {
  if ((int)blockIdx.x < teamBlocks) {
    const int team = blockIdx.x & 7;
    const int tslot = blockIdx.x >> 3;
    const int TB = teamBlocks >> 3;
    const int lo = team * N8, hi = min(N, lo + N8);
    const int Et = E + N;
    for (int e = tslot * 256 + (int)threadIdx.x; e < Et; e += TB * 256) {
      int d = (e < E) ? ei[E + e] : (e - E);
      if (d >= lo && d < hi) atomicAdd(&counts[d], 1);
    }
  } else {
    int idx = ((int)blockIdx.x - teamBlocks) * 256 + (int)threadIdx.x;
    if (idx < 256 * 256) {
      int m = idx >> 8, k = idx & 255;
      W1T[idx] = f2bf(W1[k * 256 + m]);
    } else if (idx < 256 * 256 + 64 * 256) {
      int i = idx - 256 * 256;
      int m = i >> 8, k = i & 255;
      W2T[i] = f2bf(W2[k * 64 + m]);
    }
  }
}

// ---------------- hierarchical scan (3 small launches, proven) ----------------
__global__ void block_scan_kernel(const int* __restrict__ counts, int* __restrict__ offsets,
                                  int* __restrict__ bsums, int N) {
  __shared__ int sm[256];
  int tid = threadIdx.x;
  int gid = blockIdx.x * 256 + tid;
  int v = (gid < N) ? counts[gid] : 0;
  int val = v;
  sm[tid] = val;
  __syncthreads();
  for (int off = 1; off < 256; off <<= 1) {
    int o = (tid >= off) ? sm[tid - off] : 0;
    __syncthreads();
    val += o;
    sm[tid] = val;
    __syncthreads();
  }
  if (gid < N) offsets[gid] = val - v;
  if (tid == 255) bsums[blockIdx.x] = val;
}

__global__ void scan_sums_kernel(int* __restrict__ bsums, int* __restrict__ offsets,
                                 int nb, int N) {
  __shared__ int sm[1024];
  int tid = threadIdx.x;
  int v = (tid < nb) ? bsums[tid] : 0;
  int val = v;
  sm[tid] = val;
  __syncthreads();
  for (int off = 1; off < 1024; off <<= 1) {
    int o = (tid >= off) ? sm[tid - off] : 0;
    __syncthreads();
    val += o;
    sm[tid] = val;
    __syncthreads();
  }
  if (tid < nb) bsums[tid] = val - v;
  if (tid == 1023) offsets[N] = val;
}

__global__ void add_base_kernel(int* __restrict__ offsets, int* __restrict__ cursor,
                                const int* __restrict__ bsums, int N) {
  int gid = blockIdx.x * 256 + threadIdx.x;
  if (gid >= N) return;
  int o = offsets[gid] + bsums[blockIdx.x];
  offsets[gid] = o;
  cursor[gid] = o;
}

// ---------------- scatter (XCD-team filtered) ----------------
__global__ void scatter_kernel(const int* __restrict__ ei, int E, int N, int N8,
                               int* __restrict__ cursor, int* __restrict__ csr_src,
                               int teamBlocks) {
  const int team = blockIdx.x & 7;
  const int tslot = blockIdx.x >> 3;
  const int TB = teamBlocks >> 3;
  const int lo = team * N8, hi = min(N, lo + N8);
  const int Et = E + N;
  for (int e = tslot * 256 + (int)threadIdx.x; e < Et; e += TB * 256) {
    int d = (e < E) ? ei[E + e] : (e - E);
    if (d >= lo && d < hi) {
      int s = (e < E) ? ei[e] : d;
      int pos = atomicAdd(&cursor[d], 1);
      csr_src[pos] = s;
    }
  }
}

// ---------------- MFMA GEMM: C[N][BN] = A[N][K] @ Bt[BN][K]^T, bf16 ----------------
template<int BM, int BN, int BK, int WM, int WN, bool AF32, int EPI>
__global__ __launch_bounds__(256) void mfma_gemm(const void* __restrict__ Ap,
                                                 const u16* __restrict__ Bt,
                                                 u16* __restrict__ C,
                                                 const float* __restrict__ att_s,
                                                 const float* __restrict__ att_d,
                                                 float* __restrict__ a_s,
                                                 float* __restrict__ a_d,
                                                 int N, int K) {
  constexpr int PAD = 8;
  __shared__ u16 As[BM][BK + PAD];
  __shared__ u16 Bs[BN][BK + PAD];
  const int tid = threadIdx.x;
  const int row0 = blockIdx.x * BM;
  const int w = tid >> 6, lane = tid & 63;
  const int wr = (w / (BN / WN)) * WM;
  const int wc = (w % (BN / WN)) * WN;
  constexpr int MF = WM / 16, NF = WN / 16;
  constexpr int CPR = BK / 8;
  f32x4 acc[MF][NF] = {};

  for (int k0 = 0; k0 < K; k0 += BK) {
    constexpr int ACH = BM * CPR;
#pragma unroll
    for (int c = 0; c < ACH; c += 256) {
      int cc = c + tid;
      int r = cc / CPR, kc = cc % CPR;
      int row = row0 + r;
      if (AF32) {
        const float* A = (const float*)Ap;
        float4 v0 = make_float4(0.f, 0.f, 0.f, 0.f), v1 = v0;
        if (row < N) {
          const float* p = A + (size_t)row * K + k0 + kc * 8;
          v0 = *(const float4*)p;
          v1 = *(const float4*)(p + 4);
        }
        union { __hip_bfloat162 h[4]; uint4 u; } cv;
        cv.h[0] = __float22bfloat162_rn(make_float2(v0.x, v0.y));
        cv.h[1] = __float22bfloat162_rn(make_float2(v0.z, v0.w));
        cv.h[2] = __float22bfloat162_rn(make_float2(v1.x, v1.y));
        cv.h[3] = __float22bfloat162_rn(make_float2(v1.z, v1.w));
        *(uint4*)&As[r][kc * 8] = cv.u;
      } else {
        const u16* A = (const u16*)Ap;
        uint4 v = make_uint4(0, 0, 0, 0);
        if (row < N) v = *(const uint4*)(A + (size_t)row * K + k0 + kc * 8);
        *(uint4*)&As[r][kc * 8] = v;
      }
    }
    constexpr int BCH = BN * CPR;
#pragma unroll
    for (int c = 0; c < BCH; c += 256) {
      int cc = c + tid;
      int r = cc / CPR, kc = cc % CPR;
      *(uint4*)&Bs[r][kc * 8] = *(const uint4*)(Bt + (size_t)r * K + k0 + kc * 8);
    }
    __syncthreads();
    const int lr = lane & 15, lk = (lane >> 4) * 8;
    bf8_t a[MF], b[NF];
#pragma unroll
    for (int mi = 0; mi < MF; ++mi) a[mi] = *(bf8_t*)&As[wr + mi * 16 + lr][lk];
#pragma unroll
    for (int ni = 0; ni < NF; ++ni) b[ni] = *(bf8_t*)&Bs[wc + ni * 16 + lr][lk];
#pragma unroll
    for (int mi = 0; mi < MF; ++mi)
#pragma unroll
      for (int ni = 0; ni < NF; ++ni)
        acc[mi][ni] = __builtin_amdgcn_mfma_f32_16x16x32_bf16(a[mi], b[ni], acc[mi][ni], 0, 0, 0);
    __syncthreads();
  }
  // C-write: col=lane&15, row=(lane>>4)*4+reg
#pragma unroll
  for (int mi = 0; mi < MF; ++mi)
#pragma unroll
    for (int ni = 0; ni < NF; ++ni)
#pragma unroll
      for (int r = 0; r < 4; ++r) {
        int row = row0 + wr + mi * 16 + (lane >> 4) * 4 + r;
        int col = wc + ni * 16 + (lane & 15);
        if (row < N) C[(size_t)row * BN + col] = f2bf(acc[mi][ni][r]);
      }

  // ---- fused attention-scalar epilogue ----
  if (EPI == 1) {
    __shared__ float sm_s[4][64];
    __shared__ float sm_d[4][64];
    float asl[NF], adl[NF];
#pragma unroll
    for (int ni = 0; ni < NF; ++ni) {
      asl[ni] = att_s[wc + ni * 16 + (lane & 15)];
      adl[ni] = att_d[wc + ni * 16 + (lane & 15)];
    }
#pragma unroll
    for (int mi = 0; mi < MF; ++mi)
#pragma unroll
      for (int r = 0; r < 4; ++r) {
        float ps = 0.f, pd = 0.f;
#pragma unroll
        for (int ni = 0; ni < NF; ++ni) {
          float c = acc[mi][ni][r];
          ps += c * asl[ni];
          pd += c * adl[ni];
        }
#pragma unroll
        for (int o = 1; o < 16; o <<= 1) {
          ps += __shfl_xor(ps, o);
          pd += __shfl_xor(pd, o);
        }
        if ((lane & 15) == 0) {
          int row = mi * 16 + (lane >> 4) * 4 + r;
          sm_s[w][row] = ps;
          sm_d[w][row] = pd;
        }
      }
    __syncthreads();
    if (tid < 128) {
      int row = tid & 63, head = tid >> 6;
      int grow = row0 + row;
      if (grow < N) {
        a_s[grow * 2 + head] = sm_s[head * 2 + 0][row] + sm_s[head * 2 + 1][row];
        a_d[grow * 2 + head] = sm_d[head * 2 + 0][row] + sm_d[head * 2 + 1][row];
      }
    }
  } else if (EPI == 2) {
    float asl[NF], adl[NF];
#pragma unroll
    for (int ni = 0; ni < NF; ++ni) {
      asl[ni] = att_s[ni * 16 + (lane & 15)];
      adl[ni] = att_d[ni * 16 + (lane & 15)];
    }
#pragma unroll
    for (int mi = 0; mi < MF; ++mi)
#pragma unroll
      for (int r = 0; r < 4; ++r) {
        float ps = 0.f, pd = 0.f;
#pragma unroll
        for (int ni = 0; ni < NF; ++ni) {
          float c = acc[mi][ni][r];
          ps += c * asl[ni];
          pd += c * adl[ni];
        }
#pragma unroll
        for (int o = 1; o < 16; o <<= 1) {
          ps += __shfl_xor(ps, o);
          pd += __shfl_xor(pd, o);
        }
        int row = row0 + wr + mi * 16 + (lane >> 4) * 4 + r;
        if ((lane & 15) == 0 && row < N) {
          a_s[row] = ps;
          a_d[row] = pd;
        }
      }
  }
}

// ---------------- layer-1 aggregation: channel-sliced XCD teams ----------------
// team = bid&7 -> XCD (round-robin heuristic); team owns channels [team*32, team*32+32)
// = 64B of each H1 row -> per-XCD working set 3.2MB, fits 4MB XCD L2.
// Wave = 1 node: 4 edge-groups x 16 lanes, 4B/lane (one 64B line per edge).
__global__ void agg1_kernel(const u16* __restrict__ H1, const int* __restrict__ offsets,
                            const int* __restrict__ csr_src,
                            const float* __restrict__ a_src, const float* __restrict__ a_dst,
                            const float* __restrict__ b1, u16* __restrict__ out, int N) {
  __shared__ int2 meta[4][64];
  const int team = blockIdx.x & 7;
  const int wv = threadIdx.x >> 6;
  const int lane = threadIdx.x & 63;
  const int node = ((int)blockIdx.x >> 3) * 4 + wv;
  if (node >= N) return;
  const int head = team >> 2;        // teams 0-3: channels 0..127 (head0); 4-7: head1
  const int g = lane >> 4;           // edge group 0..3
  const int l4 = lane & 15;          // channel-pair slot (4B each)
  int off = offsets[node];
  int deg = offsets[node + 1] - off;
  float ad = a_dst[node * 2 + head];
  const char* H1c = (const char*)H1;
  const unsigned coff = (unsigned)(team * 64 + l4 * 4);
  float a0 = 0.f, a1 = 0.f, den = 0.f;
  const int2* mw = meta[wv];

  auto proc = [&](int jj) {
    int2 m = mw[jj];
    float w = __int_as_float(m.y);
    unsigned u = *(const unsigned*)(H1c + (((unsigned)m.x << 9) + coff));
    den += w;
    a0 += w * bflo(u);
    a1 += w * bfhi(u);
  };

  for (int base = 0; base < deg; base += 64) {
    int i = base + lane;
    if (i < deg) {
      int s = csr_src[off + i];
      float l = a_src[s * 2 + head] + ad;
      l = l > 0.f ? l : 0.2f * l;
      meta[wv][lane] = make_int2(s, __float_as_int(__expf(l)));
    }
    int cnt = min(64, deg - base);
    int j = 0;
    for (; j + 16 <= cnt; j += 16) {
      proc(j + g); proc(j + 4 + g); proc(j + 8 + g); proc(j + 12 + g);
    }
    for (; j + 4 <= cnt; j += 4) proc(j + g);
    int r = cnt - j;
    if (g < r) proc(j + g);
  }
  // combine 4 edge-groups (lane bits 4,5)
  a0 += __shfl_xor(a0, 16); a0 += __shfl_xor(a0, 32);
  a1 += __shfl_xor(a1, 16); a1 += __shfl_xor(a1, 32);
  den += __shfl_xor(den, 16); den += __shfl_xor(den, 32);

  float inv = 1.f / (den + 1e-16f);
  float2 bb = *(const float2*)(b1 + team * 32 + l4 * 2);
  float o0 = a0 * inv + bb.x;
  float o1 = a1 * inv + bb.y;
  o0 = o0 > 0.f ? o0 : expm1f(o0);
  o1 = o1 > 0.f ? o1 : expm1f(o1);
  if (g == 0) {
    unsigned ov = (unsigned)f2bf(o0) | ((unsigned)f2bf(o1) << 16);
    *(unsigned*)((char*)out + (((size_t)node) << 9) + coff) = ov;
  }
}

// ---------------- layer-2 aggregation: 8 edges/wave-step + log_softmax ----------------
__global__ void agg2_kernel(const u16* __restrict__ H2, const int* __restrict__ offsets,
                            const int* __restrict__ csr_src,
                            const float* __restrict__ a_src, const float* __restrict__ a_dst,
                            const float* __restrict__ b2, float* __restrict__ out, int N) {
  __shared__ int2 meta[4][64];
  int wv = threadIdx.x >> 6;
  int lane = threadIdx.x & 63;
  int node = blockIdx.x * 4 + wv;
  if (node >= N) return;
  int off = offsets[node];
  int deg = offsets[node + 1] - off;
  float ad = a_dst[node];
  const int grp = lane >> 3;
  const int l3 = lane & 7;
  const char* H2c = (const char*)H2;
  const unsigned loff = (unsigned)(l3 * 16);
  float acc[8] = {0.f, 0.f, 0.f, 0.f, 0.f, 0.f, 0.f, 0.f};
  float den = 0.f;
  const int2* mw = meta[wv];

  auto proc = [&](int jj) {
    int2 m = mw[jj];
    float w = __int_as_float(m.y);
    uint4 u = *(const uint4*)(H2c + (((unsigned)m.x << 7) + loff));
    den += w;
    acc[0] += w * bflo(u.x); acc[1] += w * bfhi(u.x);
    acc[2] += w * bflo(u.y); acc[3] += w * bfhi(u.y);
    acc[4] += w * bflo(u.z); acc[5] += w * bfhi(u.z);
    acc[6] += w * bflo(u.w); acc[7] += w * bfhi(u.w);
  };

  for (int base = 0; base < deg; base += 64) {
    int i = base + lane;
    if (i < deg) {
      int s = csr_src[off + i];
      float l = a_src[s] + ad;
      l = l > 0.f ? l : 0.2f * l;
      meta[wv][lane] = make_int2(s, __float_as_int(__expf(l)));
    }
    int cnt = min(64, deg - base);
    int j = 0;
    for (; j + 16 <= cnt; j += 16) { proc(j + grp); proc(j + 8 + grp); }
    for (; j + 8 <= cnt; j += 8) proc(j + grp);
    int r = cnt - j;
    if (r > 0 && grp < r) proc(j + grp);
  }
#pragma unroll
  for (int k = 0; k < 8; ++k) {
    acc[k] += __shfl_xor(acc[k], 8);
    acc[k] += __shfl_xor(acc[k], 16);
    acc[k] += __shfl_xor(acc[k], 32);
  }
  den += __shfl_xor(den, 8);
  den += __shfl_xor(den, 16);
  den += __shfl_xor(den, 32);

  float inv = 1.f / (den + 1e-16f);
  float4 b01 = *(const float4*)(b2 + l3 * 8);
  float4 b23 = *(const float4*)(b2 + l3 * 8 + 4);
  float bb[8] = {b01.x, b01.y, b01.z, b01.w, b23.x, b23.y, b23.z, b23.w};
  float v[8];
#pragma unroll
  for (int k = 0; k < 8; ++k) v[k] = acc[k] * inv + bb[k];
  float m = v[0];
#pragma unroll
  for (int k = 1; k < 8; ++k) m = fmaxf(m, v[k]);
  m = fmaxf(m, __shfl_xor(m, 1));
  m = fmaxf(m, __shfl_xor(m, 2));
  m = fmaxf(m, __shfl_xor(m, 4));
  float sum = 0.f;
#pragma unroll
  for (int k = 0; k < 8; ++k) sum += __expf(v[k] - m);
  sum += __shfl_xor(sum, 1);
  sum += __shfl_xor(sum, 2);
  sum += __shfl_xor(sum, 4);
  float ls = m + logf(sum);
  if (lane < 8) {
    float4 o0 = make_float4(v[0] - ls, v[1] - ls, v[2] - ls, v[3] - ls);
    float4 o1 = make_float4(v[4] - ls, v[5] - ls, v[6] - ls, v[7] - ls);
    *(float4*)(out + (size_t)node * 64 + l3 * 8) = o0;
    *(float4*)(out + (size_t)node * 64 + l3 * 8 + 4) = o1;
  }
}

// ---------------- launch ----------------
extern "C" void kernel_launch(void* const* d_in, const int* in_sizes, int n_in,
                              void* d_out, int out_size, void* d_ws, size_t ws_size,
                              hipStream_t stream) {
  const float* x   = (const float*)d_in[0];
  const int*   ei  = (const int*)d_in[1];
  const float* W1  = (const float*)d_in[2];
  const float* as1 = (const float*)d_in[3];
  const float* ad1 = (const float*)d_in[4];
  const float* b1  = (const float*)d_in[5];
  const float* W2  = (const float*)d_in[6];
  const float* as2 = (const float*)d_in[7];
  const float* ad2 = (const float*)d_in[8];
  const float* b2  = (const float*)d_in[9];
  float* out = (float*)d_out;

  const int N  = in_sizes[0] / 256;
  const int E  = in_sizes[1] / 2;
  const int Et = E + N;
  const int N8 = (N + 7) / 8;
  const int nb  = (N + 255) / 256;
  const int nbt = (256 * 256 + 64 * 256 + 255) / 256;
  const int teamBlocks = 2048;

  char* p = (char*)d_ws;
  auto alloc = [&](size_t bytes) -> char* {
    char* r = p;
    p += (bytes + 255) & ~(size_t)255;
    return r;
  };
  u16* H1b     = (u16*)alloc((size_t)N * 256 * 2);
  u16* h1act   = (u16*)alloc((size_t)N * 256 * 2);
  u16* H2b     = (u16*)alloc((size_t)N * 64 * 2);
  u16* W1T     = (u16*)alloc((size_t)256 * 256 * 2);
  u16* W2T     = (u16*)alloc((size_t)64 * 256 * 2);
  float* a_src1 = (float*)alloc((size_t)N * 2 * 4);
  float* a_dst1 = (float*)alloc((size_t)N * 2 * 4);
  float* a_src2 = (float*)alloc((size_t)N * 4);
  float* a_dst2 = (float*)alloc((size_t)N * 4);
  int* counts   = (int*)alloc((size_t)N * 4);
  int* offsets  = (int*)alloc((size_t)(N + 1) * 4);
  int* cursor   = (int*)alloc((size_t)N * 4);
  int* bsums    = (int*)alloc((size_t)1024 * 4);
  int* csr_src  = (int*)alloc((size_t)Et * 4);

  const int tb = 256;

  // CSR build
  hipMemsetAsync(counts, 0, (size_t)N * 4, stream);
  prep_kernel<<<teamBlocks + nbt, tb, 0, stream>>>(ei, E, N, N8, counts, W1, W2, W1T, W2T,
                                                   teamBlocks);
  block_scan_kernel<<<nb, tb, 0, stream>>>(counts, offsets, bsums, N);
  scan_sums_kernel<<<1, 1024, 0, stream>>>(bsums, offsets, nb, N);
  add_base_kernel<<<nb, tb, 0, stream>>>(offsets, cursor, bsums, N);
  scatter_kernel<<<teamBlocks, tb, 0, stream>>>(ei, E, N, N8, cursor, csr_src, teamBlocks);

  // layer 1: gemm + fused a1
  mfma_gemm<64, 256, 32, 64, 64, true, 1><<<(N + 63) / 64, tb, 0, stream>>>(
      x, W1T, H1b, as1, ad1, a_src1, a_dst1, N, 256);
  // channel-sliced agg1: 8 teams x ceil(N/4) node-blocks
  agg1_kernel<<<((N + 3) / 4) * 8, tb, 0, stream>>>(H1b, offsets, csr_src, a_src1, a_dst1,
                                                    b1, h1act, N);

  // layer 2: gemm + fused a2
  mfma_gemm<128, 64, 32, 32, 64, false, 2><<<(N + 127) / 128, tb, 0, stream>>>(
      h1act, W2T, H2b, as2, ad2, a_src2, a_dst2, N, 256);
  agg2_kernel<<<(N + 3) / 4, tb, 0, stream>>>(H2b, offsets, csr_src, a_src2, a_dst2, b2,
                                              out, N);
}

// Round 13
// 200.677 us; speedup vs baseline: 1.5911x; 1.5911x over previous
//
#include <hip/hip_runtime.h>
#include <hip/hip_bf16.h>

typedef unsigned short u16;
typedef short bf8_t __attribute__((ext_vector_type(8)));
typedef float f32x4 __attribute__((ext_vector_type(4)));
typedef float f32x2 __attribute__((ext_vector_type(2)));

__device__ inline u16 f2bf(float f) {
  unsigned u = __float_as_uint(f);
  u += 0x7FFFu + ((u >> 16) & 1u);
  return (u16)(u >> 16);
}
__device__ inline float bf2f(u16 h) { return __uint_as_float(((unsigned)h) << 16); }
__device__ inline float bflo(unsigned u) { return __uint_as_float(u << 16); }
__device__ inline float bfhi(unsigned u) { return __uint_as_float(u & 0xffff0000u); }

// ---------------- count (XCD-team filtered) + weight transposes ----------------
__global__ void prep_kernel(const int* __restrict__ ei, int E, int N, int N8,
                            int* __restrict__ counts,
                            const float* __restrict__ W1, const float* __restrict__ W2,
                            u16* __restrict__ W1T, u16* __restrict__ W2T, int teamBlocks) {
  if ((int)blockIdx.x < teamBlocks) {
    const int team = blockIdx.x & 7;
    const int tslot = blockIdx.x >> 3;
    const int TB = teamBlocks >> 3;
    const int lo = team * N8, hi = min(N, lo + N8);
    const int Et = E + N;
    for (int e = tslot * 256 + (int)threadIdx.x; e < Et; e += TB * 256) {
      int d = (e < E) ? ei[E + e] : (e - E);
      if (d >= lo && d < hi) atomicAdd(&counts[d], 1);
    }
  } else {
    int idx = ((int)blockIdx.x - teamBlocks) * 256 + (int)threadIdx.x;
    if (idx < 256 * 256) {
      int m = idx >> 8, k = idx & 255;
      W1T[idx] = f2bf(W1[k * 256 + m]);
    } else if (idx < 256 * 256 + 64 * 256) {
      int i = idx - 256 * 256;
      int m = i >> 8, k = i & 255;
      W2T[i] = f2bf(W2[k * 64 + m]);
    }
  }
}

// ---------------- hierarchical scan (3 small launches, proven) ----------------
__global__ void block_scan_kernel(const int* __restrict__ counts, int* __restrict__ offsets,
                                  int* __restrict__ bsums, int N) {
  __shared__ int sm[256];
  int tid = threadIdx.x;
  int gid = blockIdx.x * 256 + tid;
  int v = (gid < N) ? counts[gid] : 0;
  int val = v;
  sm[tid] = val;
  __syncthreads();
  for (int off = 1; off < 256; off <<= 1) {
    int o = (tid >= off) ? sm[tid - off] : 0;
    __syncthreads();
    val += o;
    sm[tid] = val;
    __syncthreads();
  }
  if (gid < N) offsets[gid] = val - v;
  if (tid == 255) bsums[blockIdx.x] = val;
}

__global__ void scan_sums_kernel(int* __restrict__ bsums, int* __restrict__ offsets,
                                 int nb, int N) {
  __shared__ int sm[1024];
  int tid = threadIdx.x;
  int v = (tid < nb) ? bsums[tid] : 0;
  int val = v;
  sm[tid] = val;
  __syncthreads();
  for (int off = 1; off < 1024; off <<= 1) {
    int o = (tid >= off) ? sm[tid - off] : 0;
    __syncthreads();
    val += o;
    sm[tid] = val;
    __syncthreads();
  }
  if (tid < nb) bsums[tid] = val - v;
  if (tid == 1023) offsets[N] = val;
}

__global__ void add_base_kernel(int* __restrict__ offsets, int* __restrict__ cursor,
                                const int* __restrict__ bsums, int N) {
  int gid = blockIdx.x * 256 + threadIdx.x;
  if (gid >= N) return;
  int o = offsets[gid] + bsums[blockIdx.x];
  offsets[gid] = o;
  cursor[gid] = o;
}

// ---------------- scatter (XCD-team filtered) ----------------
__global__ void scatter_kernel(const int* __restrict__ ei, int E, int N, int N8,
                               int* __restrict__ cursor, int* __restrict__ csr_src,
                               int teamBlocks) {
  const int team = blockIdx.x & 7;
  const int tslot = blockIdx.x >> 3;
  const int TB = teamBlocks >> 3;
  const int lo = team * N8, hi = min(N, lo + N8);
  const int Et = E + N;
  for (int e = tslot * 256 + (int)threadIdx.x; e < Et; e += TB * 256) {
    int d = (e < E) ? ei[E + e] : (e - E);
    if (d >= lo && d < hi) {
      int s = (e < E) ? ei[e] : d;
      int pos = atomicAdd(&cursor[d], 1);
      csr_src[pos] = s;
    }
  }
}

// ---------------- MFMA GEMM: C[N][BN] = A[N][K] @ Bt[BN][K]^T, bf16 ----------------
// EPI 1: layer1 — C written as fp8 e4m3 (agg1's gather halves); attention epilogue 2-head.
// EPI 2: layer2 — C written bf16; attention epilogue 1-head in-wave.
template<int BM, int BN, int BK, int WM, int WN, bool AF32, int EPI>
__global__ __launch_bounds__(256) void mfma_gemm(const void* __restrict__ Ap,
                                                 const u16* __restrict__ Bt,
                                                 u16* __restrict__ C,
                                                 const float* __restrict__ att_s,
                                                 const float* __restrict__ att_d,
                                                 float* __restrict__ a_s,
                                                 float* __restrict__ a_d,
                                                 int N, int K) {
  constexpr int PAD = 8;
  __shared__ u16 As[BM][BK + PAD];
  __shared__ u16 Bs[BN][BK + PAD];
  const int tid = threadIdx.x;
  const int row0 = blockIdx.x * BM;
  const int w = tid >> 6, lane = tid & 63;
  const int wr = (w / (BN / WN)) * WM;
  const int wc = (w % (BN / WN)) * WN;
  constexpr int MF = WM / 16, NF = WN / 16;
  constexpr int CPR = BK / 8;
  f32x4 acc[MF][NF] = {};

  for (int k0 = 0; k0 < K; k0 += BK) {
    constexpr int ACH = BM * CPR;
#pragma unroll
    for (int c = 0; c < ACH; c += 256) {
      int cc = c + tid;
      int r = cc / CPR, kc = cc % CPR;
      int row = row0 + r;
      if (AF32) {
        const float* A = (const float*)Ap;
        float4 v0 = make_float4(0.f, 0.f, 0.f, 0.f), v1 = v0;
        if (row < N) {
          const float* p = A + (size_t)row * K + k0 + kc * 8;
          v0 = *(const float4*)p;
          v1 = *(const float4*)(p + 4);
        }
        union { __hip_bfloat162 h[4]; uint4 u; } cv;
        cv.h[0] = __float22bfloat162_rn(make_float2(v0.x, v0.y));
        cv.h[1] = __float22bfloat162_rn(make_float2(v0.z, v0.w));
        cv.h[2] = __float22bfloat162_rn(make_float2(v1.x, v1.y));
        cv.h[3] = __float22bfloat162_rn(make_float2(v1.z, v1.w));
        *(uint4*)&As[r][kc * 8] = cv.u;
      } else {
        const u16* A = (const u16*)Ap;
        uint4 v = make_uint4(0, 0, 0, 0);
        if (row < N) v = *(const uint4*)(A + (size_t)row * K + k0 + kc * 8);
        *(uint4*)&As[r][kc * 8] = v;
      }
    }
    constexpr int BCH = BN * CPR;
#pragma unroll
    for (int c = 0; c < BCH; c += 256) {
      int cc = c + tid;
      int r = cc / CPR, kc = cc % CPR;
      *(uint4*)&Bs[r][kc * 8] = *(const uint4*)(Bt + (size_t)r * K + k0 + kc * 8);
    }
    __syncthreads();
    const int lr = lane & 15, lk = (lane >> 4) * 8;
    bf8_t a[MF], b[NF];
#pragma unroll
    for (int mi = 0; mi < MF; ++mi) a[mi] = *(bf8_t*)&As[wr + mi * 16 + lr][lk];
#pragma unroll
    for (int ni = 0; ni < NF; ++ni) b[ni] = *(bf8_t*)&Bs[wc + ni * 16 + lr][lk];
#pragma unroll
    for (int mi = 0; mi < MF; ++mi)
#pragma unroll
      for (int ni = 0; ni < NF; ++ni)
        acc[mi][ni] = __builtin_amdgcn_mfma_f32_16x16x32_bf16(a[mi], b[ni], acc[mi][ni], 0, 0, 0);
    __syncthreads();
  }
  // C-write: col=lane&15, row=(lane>>4)*4+reg
  unsigned char* C8 = (unsigned char*)C;
#pragma unroll
  for (int mi = 0; mi < MF; ++mi)
#pragma unroll
    for (int ni = 0; ni < NF; ++ni)
#pragma unroll
      for (int r = 0; r < 4; ++r) {
        int row = row0 + wr + mi * 16 + (lane >> 4) * 4 + r;
        int col = wc + ni * 16 + (lane & 15);
        if (row < N) {
          if (EPI == 1) {
            int p8 = __builtin_amdgcn_cvt_pk_fp8_f32(acc[mi][ni][r], acc[mi][ni][r], 0, false);
            C8[(size_t)row * BN + col] = (unsigned char)(p8 & 0xff);
          } else {
            C[(size_t)row * BN + col] = f2bf(acc[mi][ni][r]);
          }
        }
      }

  // ---- fused attention-scalar epilogue (fp32 acc, unaffected by fp8 storage) ----
  if (EPI == 1) {
    __shared__ float sm_s[4][64];
    __shared__ float sm_d[4][64];
    float asl[NF], adl[NF];
#pragma unroll
    for (int ni = 0; ni < NF; ++ni) {
      asl[ni] = att_s[wc + ni * 16 + (lane & 15)];
      adl[ni] = att_d[wc + ni * 16 + (lane & 15)];
    }
#pragma unroll
    for (int mi = 0; mi < MF; ++mi)
#pragma unroll
      for (int r = 0; r < 4; ++r) {
        float ps = 0.f, pd = 0.f;
#pragma unroll
        for (int ni = 0; ni < NF; ++ni) {
          float c = acc[mi][ni][r];
          ps += c * asl[ni];
          pd += c * adl[ni];
        }
#pragma unroll
        for (int o = 1; o < 16; o <<= 1) {
          ps += __shfl_xor(ps, o);
          pd += __shfl_xor(pd, o);
        }
        if ((lane & 15) == 0) {
          int row = mi * 16 + (lane >> 4) * 4 + r;
          sm_s[w][row] = ps;
          sm_d[w][row] = pd;
        }
      }
    __syncthreads();
    if (tid < 128) {
      int row = tid & 63, head = tid >> 6;
      int grow = row0 + row;
      if (grow < N) {
        a_s[grow * 2 + head] = sm_s[head * 2 + 0][row] + sm_s[head * 2 + 1][row];
        a_d[grow * 2 + head] = sm_d[head * 2 + 0][row] + sm_d[head * 2 + 1][row];
      }
    }
  } else if (EPI == 2) {
    float asl[NF], adl[NF];
#pragma unroll
    for (int ni = 0; ni < NF; ++ni) {
      asl[ni] = att_s[ni * 16 + (lane & 15)];
      adl[ni] = att_d[ni * 16 + (lane & 15)];
    }
#pragma unroll
    for (int mi = 0; mi < MF; ++mi)
#pragma unroll
      for (int r = 0; r < 4; ++r) {
        float ps = 0.f, pd = 0.f;
#pragma unroll
        for (int ni = 0; ni < NF; ++ni) {
          float c = acc[mi][ni][r];
          ps += c * asl[ni];
          pd += c * adl[ni];
        }
#pragma unroll
        for (int o = 1; o < 16; o <<= 1) {
          ps += __shfl_xor(ps, o);
          pd += __shfl_xor(pd, o);
        }
        int row = row0 + wr + mi * 16 + (lane >> 4) * 4 + r;
        if ((lane & 15) == 0 && row < N) {
          a_s[row] = ps;
          a_d[row] = pd;
        }
      }
  }
}

// ---------------- layer-1 aggregation: fp8 gather (4B/lane = 4ch), 4x unroll ----------------
__global__ void agg1_kernel(const unsigned char* __restrict__ H1, const int* __restrict__ offsets,
                            const int* __restrict__ csr_src,
                            const float* __restrict__ a_src, const float* __restrict__ a_dst,
                            const float* __restrict__ b1, u16* __restrict__ out, int N) {
  __shared__ int4 meta[4][64];
  int wv = threadIdx.x >> 6;
  int lane = threadIdx.x & 63;
  int node = blockIdx.x * 4 + wv;
  if (node >= N) return;
  int off = offsets[node];
  int deg = offsets[node + 1] - off;
  float ad0 = a_dst[node * 2 + 0];
  float ad1 = a_dst[node * 2 + 1];
  bool hi = lane >= 32;  // channels lane*4 >= 128 -> head 1
  const unsigned loff = (unsigned)(lane * 4);
  float4 acc = make_float4(0.f, 0.f, 0.f, 0.f);
  float den = 0.f;
  const int4* mw = meta[wv];

  auto proc = [&](int4 m) {
    float w = hi ? __int_as_float(m.z) : __int_as_float(m.y);
    unsigned u = *(const unsigned*)(H1 + (((unsigned)m.x << 8) + loff));
    f32x2 lo2 = __builtin_amdgcn_cvt_pk_f32_fp8(u, false);
    f32x2 hi2 = __builtin_amdgcn_cvt_pk_f32_fp8(u, true);
    den += w;
    acc.x += w * lo2.x;
    acc.y += w * lo2.y;
    acc.z += w * hi2.x;
    acc.w += w * hi2.y;
  };

  for (int base = 0; base < deg; base += 64) {
    int i = base + lane;
    if (i < deg) {
      int s = csr_src[off + i];
      float l0 = a_src[s * 2 + 0] + ad0;
      float l1 = a_src[s * 2 + 1] + ad1;
      l0 = l0 > 0.f ? l0 : 0.2f * l0;
      l1 = l1 > 0.f ? l1 : 0.2f * l1;
      meta[wv][lane] = make_int4(s, __float_as_int(__expf(l0)), __float_as_int(__expf(l1)), 0);
    }
    int cnt = min(64, deg - base);
    int j = 0;
    for (; j + 4 <= cnt; j += 4) {
      int4 m0 = mw[j], m1 = mw[j + 1], m2 = mw[j + 2], m3 = mw[j + 3];
      proc(m0); proc(m1); proc(m2); proc(m3);
    }
    for (; j < cnt; ++j) proc(mw[j]);
  }
  float inv = 1.f / (den + 1e-16f);
  float4 bb = *(const float4*)(b1 + lane * 4);
  float o0 = acc.x * inv + bb.x;
  float o1 = acc.y * inv + bb.y;
  float o2 = acc.z * inv + bb.z;
  float o3 = acc.w * inv + bb.w;
  o0 = o0 > 0.f ? o0 : expm1f(o0);
  o1 = o1 > 0.f ? o1 : expm1f(o1);
  o2 = o2 > 0.f ? o2 : expm1f(o2);
  o3 = o3 > 0.f ? o3 : expm1f(o3);
  uint2 ov;
  ov.x = (unsigned)f2bf(o0) | ((unsigned)f2bf(o1) << 16);
  ov.y = (unsigned)f2bf(o2) | ((unsigned)f2bf(o3) << 16);
  *(uint2*)(out + (size_t)node * 256 + lane * 4) = ov;
}

// ---------------- layer-2 aggregation: 8 edges/wave-step + log_softmax ----------------
__global__ void agg2_kernel(const u16* __restrict__ H2, const int* __restrict__ offsets,
                            const int* __restrict__ csr_src,
                            const float* __restrict__ a_src, const float* __restrict__ a_dst,
                            const float* __restrict__ b2, float* __restrict__ out, int N) {
  __shared__ int2 meta[4][64];
  int wv = threadIdx.x >> 6;
  int lane = threadIdx.x & 63;
  int node = blockIdx.x * 4 + wv;
  if (node >= N) return;
  int off = offsets[node];
  int deg = offsets[node + 1] - off;
  float ad = a_dst[node];
  const int grp = lane >> 3;
  const int l3 = lane & 7;
  const char* H2c = (const char*)H2;
  const unsigned loff = (unsigned)(l3 * 16);
  float acc[8] = {0.f, 0.f, 0.f, 0.f, 0.f, 0.f, 0.f, 0.f};
  float den = 0.f;
  const int2* mw = meta[wv];

  auto proc = [&](int jj) {
    int2 m = mw[jj];
    float w = __int_as_float(m.y);
    uint4 u = *(const uint4*)(H2c + (((unsigned)m.x << 7) + loff));
    den += w;
    acc[0] += w * bflo(u.x); acc[1] += w * bfhi(u.x);
    acc[2] += w * bflo(u.y); acc[3] += w * bfhi(u.y);
    acc[4] += w * bflo(u.z); acc[5] += w * bfhi(u.z);
    acc[6] += w * bflo(u.w); acc[7] += w * bfhi(u.w);
  };

  for (int base = 0; base < deg; base += 64) {
    int i = base + lane;
    if (i < deg) {
      int s = csr_src[off + i];
      float l = a_src[s] + ad;
      l = l > 0.f ? l : 0.2f * l;
      meta[wv][lane] = make_int2(s, __float_as_int(__expf(l)));
    }
    int cnt = min(64, deg - base);
    int j = 0;
    for (; j + 16 <= cnt; j += 16) { proc(j + grp); proc(j + 8 + grp); }
    for (; j + 8 <= cnt; j += 8) proc(j + grp);
    int r = cnt - j;
    if (r > 0 && grp < r) proc(j + grp);
  }
#pragma unroll
  for (int k = 0; k < 8; ++k) {
    acc[k] += __shfl_xor(acc[k], 8);
    acc[k] += __shfl_xor(acc[k], 16);
    acc[k] += __shfl_xor(acc[k], 32);
  }
  den += __shfl_xor(den, 8);
  den += __shfl_xor(den, 16);
  den += __shfl_xor(den, 32);

  float inv = 1.f / (den + 1e-16f);
  float4 b01 = *(const float4*)(b2 + l3 * 8);
  float4 b23 = *(const float4*)(b2 + l3 * 8 + 4);
  float bb[8] = {b01.x, b01.y, b01.z, b01.w, b23.x, b23.y, b23.z, b23.w};
  float v[8];
#pragma unroll
  for (int k = 0; k < 8; ++k) v[k] = acc[k] * inv + bb[k];
  float m = v[0];
#pragma unroll
  for (int k = 1; k < 8; ++k) m = fmaxf(m, v[k]);
  m = fmaxf(m, __shfl_xor(m, 1));
  m = fmaxf(m, __shfl_xor(m, 2));
  m = fmaxf(m, __shfl_xor(m, 4));
  float sum = 0.f;
#pragma unroll
  for (int k = 0; k < 8; ++k) sum += __expf(v[k] - m);
  sum += __shfl_xor(sum, 1);
  sum += __shfl_xor(sum, 2);
  sum += __shfl_xor(sum, 4);
  float ls = m + logf(sum);
  if (lane < 8) {
    float4 o0 = make_float4(v[0] - ls, v[1] - ls, v[2] - ls, v[3] - ls);
    float4 o1 = make_float4(v[4] - ls, v[5] - ls, v[6] - ls, v[7] - ls);
    *(float4*)(out + (size_t)node * 64 + l3 * 8) = o0;
    *(float4*)(out + (size_t)node * 64 + l3 * 8 + 4) = o1;
  }
}

// ---------------- launch ----------------
extern "C" void kernel_launch(void* const* d_in, const int* in_sizes, int n_in,
                              void* d_out, int out_size, void* d_ws, size_t ws_size,
                              hipStream_t stream) {
  const float* x   = (const float*)d_in[0];
  const int*   ei  = (const int*)d_in[1];
  const float* W1  = (const float*)d_in[2];
  const float* as1 = (const float*)d_in[3];
  const float* ad1 = (const float*)d_in[4];
  const float* b1  = (const float*)d_in[5];
  const float* W2  = (const float*)d_in[6];
  const float* as2 = (const float*)d_in[7];
  const float* ad2 = (const float*)d_in[8];
  const float* b2  = (const float*)d_in[9];
  float* out = (float*)d_out;

  const int N  = in_sizes[0] / 256;
  const int E  = in_sizes[1] / 2;
  const int Et = E + N;
  const int N8 = (N + 7) / 8;
  const int nb  = (N + 255) / 256;
  const int nbt = (256 * 256 + 64 * 256 + 255) / 256;
  const int teamBlocks = 2048;

  char* p = (char*)d_ws;
  auto alloc = [&](size_t bytes) -> char* {
    char* r = p;
    p += (bytes + 255) & ~(size_t)255;
    return r;
  };
  unsigned char* H1b = (unsigned char*)alloc((size_t)N * 256);  // fp8 e4m3
  u16* h1act   = (u16*)alloc((size_t)N * 256 * 2);
  u16* H2b     = (u16*)alloc((size_t)N * 64 * 2);
  u16* W1T     = (u16*)alloc((size_t)256 * 256 * 2);
  u16* W2T     = (u16*)alloc((size_t)64 * 256 * 2);
  float* a_src1 = (float*)alloc((size_t)N * 2 * 4);
  float* a_dst1 = (float*)alloc((size_t)N * 2 * 4);
  float* a_src2 = (float*)alloc((size_t)N * 4);
  float* a_dst2 = (float*)alloc((size_t)N * 4);
  int* counts   = (int*)alloc((size_t)N * 4);
  int* offsets  = (int*)alloc((size_t)(N + 1) * 4);
  int* cursor   = (int*)alloc((size_t)N * 4);
  int* bsums    = (int*)alloc((size_t)1024 * 4);
  int* csr_src  = (int*)alloc((size_t)Et * 4);

  const int tb = 256;

  // CSR build
  hipMemsetAsync(counts, 0, (size_t)N * 4, stream);
  prep_kernel<<<teamBlocks + nbt, tb, 0, stream>>>(ei, E, N, N8, counts, W1, W2, W1T, W2T,
                                                   teamBlocks);
  block_scan_kernel<<<nb, tb, 0, stream>>>(counts, offsets, bsums, N);
  scan_sums_kernel<<<1, 1024, 0, stream>>>(bsums, offsets, nb, N);
  add_base_kernel<<<nb, tb, 0, stream>>>(offsets, cursor, bsums, N);
  scatter_kernel<<<teamBlocks, tb, 0, stream>>>(ei, E, N, N8, cursor, csr_src, teamBlocks);

  // layer 1: gemm + fused a1 (C written fp8)
  mfma_gemm<64, 256, 32, 64, 64, true, 1><<<(N + 63) / 64, tb, 0, stream>>>(
      x, W1T, (u16*)H1b, as1, ad1, a_src1, a_dst1, N, 256);
  agg1_kernel<<<(N + 3) / 4, tb, 0, stream>>>(H1b, offsets, csr_src, a_src1, a_dst1, b1,
                                              h1act, N);

  // layer 2: gemm + fused a2
  mfma_gemm<128, 64, 32, 32, 64, false, 2><<<(N + 127) / 128, tb, 0, stream>>>(
      h1act, W2T, H2b, as2, ad2, a_src2, a_dst2, N, 256);
  agg2_kernel<<<(N + 3) / 4, tb, 0, stream>>>(H2b, offsets, csr_src, a_src2, a_dst2, b2,
                                              out, N);
}

// Round 14
// 197.792 us; speedup vs baseline: 1.6143x; 1.0146x over previous
//
#include <hip/hip_runtime.h>
#include <hip/hip_bf16.h>

typedef unsigned short u16;
typedef short bf8_t __attribute__((ext_vector_type(8)));
typedef float f32x4 __attribute__((ext_vector_type(4)));
typedef float f32x2 __attribute__((ext_vector_type(2)));

__device__ inline u16 f2bf(float f) {
  unsigned u = __float_as_uint(f);
  u += 0x7FFFu + ((u >> 16) & 1u);
  return (u16)(u >> 16);
}
__device__ inline float bf2f(u16 h) { return __uint_as_float(((unsigned)h) << 16); }
__device__ inline float bflo(unsigned u) { return __uint_as_float(u << 16); }
__device__ inline float bfhi(unsigned u) { return __uint_as_float(u & 0xffff0000u); }

// ---------------- count (XCD-team filtered) + weight transposes ----------------
__global__ void prep_kernel(const int* __restrict__ ei, int E, int N, int N8,
                            int* __restrict__ counts,
                            const float* __restrict__ W1, const float* __restrict__ W2,
                            u16* __restrict__ W1T, u16* __restrict__ W2T, int teamBlocks) {
  if ((int)blockIdx.x < teamBlocks) {
    const int team = blockIdx.x & 7;
    const int tslot = blockIdx.x >> 3;
    const int TB = teamBlocks >> 3;
    const int lo = team * N8, hi = min(N, lo + N8);
    const int Et = E + N;
    for (int e = tslot * 256 + (int)threadIdx.x; e < Et; e += TB * 256) {
      int d = (e < E) ? ei[E + e] : (e - E);
      if (d >= lo && d < hi) atomicAdd(&counts[d], 1);
    }
  } else {
    int idx = ((int)blockIdx.x - teamBlocks) * 256 + (int)threadIdx.x;
    if (idx < 256 * 256) {
      int m = idx >> 8, k = idx & 255;
      W1T[idx] = f2bf(W1[k * 256 + m]);
    } else if (idx < 256 * 256 + 64 * 256) {
      int i = idx - 256 * 256;
      int m = i >> 8, k = i & 255;
      W2T[i] = f2bf(W2[k * 64 + m]);
    }
  }
}

// ---------------- hierarchical scan ----------------
__global__ void block_scan_kernel(const int* __restrict__ counts, int* __restrict__ offsets,
                                  int* __restrict__ bsums, int N) {
  __shared__ int sm[256];
  int tid = threadIdx.x;
  int gid = blockIdx.x * 256 + tid;
  int v = (gid < N) ? counts[gid] : 0;
  int val = v;
  sm[tid] = val;
  __syncthreads();
  for (int off = 1; off < 256; off <<= 1) {
    int o = (tid >= off) ? sm[tid - off] : 0;
    __syncthreads();
    val += o;
    sm[tid] = val;
    __syncthreads();
  }
  if (gid < N) offsets[gid] = val - v;
  if (tid == 255) bsums[blockIdx.x] = val;
}

__global__ void scan_sums_kernel(int* __restrict__ bsums, int* __restrict__ offsets,
                                 int nb, int N) {
  __shared__ int sm[1024];
  int tid = threadIdx.x;
  int v = (tid < nb) ? bsums[tid] : 0;
  int val = v;
  sm[tid] = val;
  __syncthreads();
  for (int off = 1; off < 1024; off <<= 1) {
    int o = (tid >= off) ? sm[tid - off] : 0;
    __syncthreads();
    val += o;
    sm[tid] = val;
    __syncthreads();
  }
  if (tid < nb) bsums[tid] = val - v;
  if (tid == 1023) offsets[N] = val;
}

__global__ void add_base_kernel(int* __restrict__ offsets, int* __restrict__ cursor,
                                const int* __restrict__ bsums, int N) {
  int gid = blockIdx.x * 256 + threadIdx.x;
  if (gid >= N) return;
  int o = offsets[gid] + bsums[blockIdx.x];
  offsets[gid] = o;
  cursor[gid] = o;
}

// ---------------- scatter (XCD-team filtered) ----------------
__global__ void scatter_kernel(const int* __restrict__ ei, int E, int N, int N8,
                               int* __restrict__ cursor, int* __restrict__ csr_src,
                               int teamBlocks) {
  const int team = blockIdx.x & 7;
  const int tslot = blockIdx.x >> 3;
  const int TB = teamBlocks >> 3;
  const int lo = team * N8, hi = min(N, lo + N8);
  const int Et = E + N;
  for (int e = tslot * 256 + (int)threadIdx.x; e < Et; e += TB * 256) {
    int d = (e < E) ? ei[E + e] : (e - E);
    if (d >= lo && d < hi) {
      int s = (e < E) ? ei[e] : d;
      int pos = atomicAdd(&cursor[d], 1);
      csr_src[pos] = s;
    }
  }
}

// ---------------- MFMA GEMM: C[N][Mtot] tile (BM x BN) at (blockIdx.x, blockIdx.y) ----------------
// EPI 1: layer1 — C written fp8 e4m3; block y covers one head (BN=128); 2x2 wave grid.
// EPI 2: layer2 — C written bf16; 1 head in-wave epilogue.
template<int BM, int BN, int BK, int WM, int WN, bool AF32, int EPI>
__global__ __launch_bounds__(256) void mfma_gemm(const void* __restrict__ Ap,
                                                 const u16* __restrict__ Bt,
                                                 u16* __restrict__ C,
                                                 const float* __restrict__ att_s,
                                                 const float* __restrict__ att_d,
                                                 float* __restrict__ a_s,
                                                 float* __restrict__ a_d,
                                                 int N, int K, int Mtot) {
  constexpr int PAD = 8;
  __shared__ u16 As[BM][BK + PAD];
  __shared__ u16 Bs[BN][BK + PAD];
  const int tid = threadIdx.x;
  const int row0 = blockIdx.x * BM;
  const int col0 = blockIdx.y * BN;
  const int w = tid >> 6, lane = tid & 63;
  const int wr = (w / (BN / WN)) * WM;
  const int wc = (w % (BN / WN)) * WN;
  constexpr int MF = WM / 16, NF = WN / 16;
  constexpr int CPR = BK / 8;
  f32x4 acc[MF][NF] = {};

  for (int k0 = 0; k0 < K; k0 += BK) {
    constexpr int ACH = BM * CPR;
#pragma unroll
    for (int c = 0; c < ACH; c += 256) {
      int cc = c + tid;
      int r = cc / CPR, kc = cc % CPR;
      int row = row0 + r;
      if (AF32) {
        const float* A = (const float*)Ap;
        float4 v0 = make_float4(0.f, 0.f, 0.f, 0.f), v1 = v0;
        if (row < N) {
          const float* p = A + (size_t)row * K + k0 + kc * 8;
          v0 = *(const float4*)p;
          v1 = *(const float4*)(p + 4);
        }
        union { __hip_bfloat162 h[4]; uint4 u; } cv;
        cv.h[0] = __float22bfloat162_rn(make_float2(v0.x, v0.y));
        cv.h[1] = __float22bfloat162_rn(make_float2(v0.z, v0.w));
        cv.h[2] = __float22bfloat162_rn(make_float2(v1.x, v1.y));
        cv.h[3] = __float22bfloat162_rn(make_float2(v1.z, v1.w));
        *(uint4*)&As[r][kc * 8] = cv.u;
      } else {
        const u16* A = (const u16*)Ap;
        uint4 v = make_uint4(0, 0, 0, 0);
        if (row < N) v = *(const uint4*)(A + (size_t)row * K + k0 + kc * 8);
        *(uint4*)&As[r][kc * 8] = v;
      }
    }
    constexpr int BCH = BN * CPR;
#pragma unroll
    for (int c = 0; c < BCH; c += 256) {
      int cc = c + tid;
      int r = cc / CPR, kc = cc % CPR;
      *(uint4*)&Bs[r][kc * 8] = *(const uint4*)(Bt + (size_t)(col0 + r) * K + k0 + kc * 8);
    }
    __syncthreads();
    const int lr = lane & 15, lk = (lane >> 4) * 8;
    bf8_t a[MF], b[NF];
#pragma unroll
    for (int mi = 0; mi < MF; ++mi) a[mi] = *(bf8_t*)&As[wr + mi * 16 + lr][lk];
#pragma unroll
    for (int ni = 0; ni < NF; ++ni) b[ni] = *(bf8_t*)&Bs[wc + ni * 16 + lr][lk];
#pragma unroll
    for (int mi = 0; mi < MF; ++mi)
#pragma unroll
      for (int ni = 0; ni < NF; ++ni)
        acc[mi][ni] = __builtin_amdgcn_mfma_f32_16x16x32_bf16(a[mi], b[ni], acc[mi][ni], 0, 0, 0);
    __syncthreads();
  }
  // C-write: col=lane&15, row=(lane>>4)*4+reg
  unsigned char* C8 = (unsigned char*)C;
#pragma unroll
  for (int mi = 0; mi < MF; ++mi)
#pragma unroll
    for (int ni = 0; ni < NF; ++ni)
#pragma unroll
      for (int r = 0; r < 4; ++r) {
        int row = row0 + wr + mi * 16 + (lane >> 4) * 4 + r;
        int col = col0 + wc + ni * 16 + (lane & 15);
        if (row < N) {
          if (EPI == 1) {
            int p8 = __builtin_amdgcn_cvt_pk_fp8_f32(acc[mi][ni][r], acc[mi][ni][r], 0, false);
            C8[(size_t)row * Mtot + col] = (unsigned char)(p8 & 0xff);
          } else {
            C[(size_t)row * Mtot + col] = f2bf(acc[mi][ni][r]);
          }
        }
      }

  // ---- fused attention-scalar epilogue ----
  if (EPI == 1) {
    // block covers one head: channels [col0, col0+BN); waves 2x2 (WM=32, WN=64)
    __shared__ float sm_s[4][64];
    __shared__ float sm_d[4][64];
    float asl[NF], adl[NF];
#pragma unroll
    for (int ni = 0; ni < NF; ++ni) {
      asl[ni] = att_s[col0 + wc + ni * 16 + (lane & 15)];
      adl[ni] = att_d[col0 + wc + ni * 16 + (lane & 15)];
    }
#pragma unroll
    for (int mi = 0; mi < MF; ++mi)
#pragma unroll
      for (int r = 0; r < 4; ++r) {
        float ps = 0.f, pd = 0.f;
#pragma unroll
        for (int ni = 0; ni < NF; ++ni) {
          float c = acc[mi][ni][r];
          ps += c * asl[ni];
          pd += c * adl[ni];
        }
#pragma unroll
        for (int o = 1; o < 16; o <<= 1) {
          ps += __shfl_xor(ps, o);
          pd += __shfl_xor(pd, o);
        }
        if ((lane & 15) == 0) {
          int row = wr + mi * 16 + (lane >> 4) * 4 + r;  // 0..63 within block
          sm_s[w][row] = ps;
          sm_d[w][row] = pd;
        }
      }
    __syncthreads();
    if (tid < 64) {
      int row = tid;
      int base = (row >> 5) * 2;  // rows 0-31 -> waves 0,1 ; rows 32-63 -> waves 2,3
      int grow = row0 + row;
      if (grow < N) {
        a_s[grow * 2 + blockIdx.y] = sm_s[base][row] + sm_s[base + 1][row];
        a_d[grow * 2 + blockIdx.y] = sm_d[base][row] + sm_d[base + 1][row];
      }
    }
  } else if (EPI == 2) {
    float asl[NF], adl[NF];
#pragma unroll
    for (int ni = 0; ni < NF; ++ni) {
      asl[ni] = att_s[ni * 16 + (lane & 15)];
      adl[ni] = att_d[ni * 16 + (lane & 15)];
    }
#pragma unroll
    for (int mi = 0; mi < MF; ++mi)
#pragma unroll
      for (int r = 0; r < 4; ++r) {
        float ps = 0.f, pd = 0.f;
#pragma unroll
        for (int ni = 0; ni < NF; ++ni) {
          float c = acc[mi][ni][r];
          ps += c * asl[ni];
          pd += c * adl[ni];
        }
#pragma unroll
        for (int o = 1; o < 16; o <<= 1) {
          ps += __shfl_xor(ps, o);
          pd += __shfl_xor(pd, o);
        }
        int row = row0 + wr + mi * 16 + (lane >> 4) * 4 + r;
        if ((lane & 15) == 0 && row < N) {
          a_s[row] = ps;
          a_d[row] = pd;
        }
      }
  }
}

// ---------------- layer-1 aggregation: fp8 gather (4B/lane = 4ch), 4x unroll ----------------
__global__ void agg1_kernel(const unsigned char* __restrict__ H1, const int* __restrict__ offsets,
                            const int* __restrict__ csr_src,
                            const float* __restrict__ a_src, const float* __restrict__ a_dst,
                            const float* __restrict__ b1, u16* __restrict__ out, int N) {
  __shared__ int4 meta[4][64];
  int wv = threadIdx.x >> 6;
  int lane = threadIdx.x & 63;
  int node = blockIdx.x * 4 + wv;
  if (node >= N) return;
  int off = offsets[node];
  int deg = offsets[node + 1] - off;
  float ad0 = a_dst[node * 2 + 0];
  float ad1 = a_dst[node * 2 + 1];
  bool hi = lane >= 32;
  const unsigned loff = (unsigned)(lane * 4);
  float4 acc = make_float4(0.f, 0.f, 0.f, 0.f);
  float den = 0.f;
  const int4* mw = meta[wv];

  auto proc = [&](int4 m) {
    float w = hi ? __int_as_float(m.z) : __int_as_float(m.y);
    unsigned u = *(const unsigned*)(H1 + (((unsigned)m.x << 8) + loff));
    f32x2 lo2 = __builtin_amdgcn_cvt_pk_f32_fp8(u, false);
    f32x2 hi2 = __builtin_amdgcn_cvt_pk_f32_fp8(u, true);
    den += w;
    acc.x += w * lo2.x;
    acc.y += w * lo2.y;
    acc.z += w * hi2.x;
    acc.w += w * hi2.y;
  };

  for (int base = 0; base < deg; base += 64) {
    int i = base + lane;
    if (i < deg) {
      int s = csr_src[off + i];
      float l0 = a_src[s * 2 + 0] + ad0;
      float l1 = a_src[s * 2 + 1] + ad1;
      l0 = l0 > 0.f ? l0 : 0.2f * l0;
      l1 = l1 > 0.f ? l1 : 0.2f * l1;
      meta[wv][lane] = make_int4(s, __float_as_int(__expf(l0)), __float_as_int(__expf(l1)), 0);
    }
    int cnt = min(64, deg - base);
    int j = 0;
    for (; j + 4 <= cnt; j += 4) {
      int4 m0 = mw[j], m1 = mw[j + 1], m2 = mw[j + 2], m3 = mw[j + 3];
      proc(m0); proc(m1); proc(m2); proc(m3);
    }
    for (; j < cnt; ++j) proc(mw[j]);
  }
  float inv = 1.f / (den + 1e-16f);
  float4 bb = *(const float4*)(b1 + lane * 4);
  float o0 = acc.x * inv + bb.x;
  float o1 = acc.y * inv + bb.y;
  float o2 = acc.z * inv + bb.z;
  float o3 = acc.w * inv + bb.w;
  o0 = o0 > 0.f ? o0 : expm1f(o0);
  o1 = o1 > 0.f ? o1 : expm1f(o1);
  o2 = o2 > 0.f ? o2 : expm1f(o2);
  o3 = o3 > 0.f ? o3 : expm1f(o3);
  uint2 ov;
  ov.x = (unsigned)f2bf(o0) | ((unsigned)f2bf(o1) << 16);
  ov.y = (unsigned)f2bf(o2) | ((unsigned)f2bf(o3) << 16);
  *(uint2*)(out + (size_t)node * 256 + lane * 4) = ov;
}

// ---------------- layer-2 aggregation: 8 edges/wave-step + log_softmax ----------------
__global__ void agg2_kernel(const u16* __restrict__ H2, const int* __restrict__ offsets,
                            const int* __restrict__ csr_src,
                            const float* __restrict__ a_src, const float* __restrict__ a_dst,
                            const float* __restrict__ b2, float* __restrict__ out, int N) {
  __shared__ int2 meta[4][64];
  int wv = threadIdx.x >> 6;
  int lane = threadIdx.x & 63;
  int node = blockIdx.x * 4 + wv;
  if (node >= N) return;
  int off = offsets[node];
  int deg = offsets[node + 1] - off;
  float ad = a_dst[node];
  const int grp = lane >> 3;
  const int l3 = lane & 7;
  const char* H2c = (const char*)H2;
  const unsigned loff = (unsigned)(l3 * 16);
  float acc[8] = {0.f, 0.f, 0.f, 0.f, 0.f, 0.f, 0.f, 0.f};
  float den = 0.f;
  const int2* mw = meta[wv];

  auto proc = [&](int jj) {
    int2 m = mw[jj];
    float w = __int_as_float(m.y);
    uint4 u = *(const uint4*)(H2c + (((unsigned)m.x << 7) + loff));
    den += w;
    acc[0] += w * bflo(u.x); acc[1] += w * bfhi(u.x);
    acc[2] += w * bflo(u.y); acc[3] += w * bfhi(u.y);
    acc[4] += w * bflo(u.z); acc[5] += w * bfhi(u.z);
    acc[6] += w * bflo(u.w); acc[7] += w * bfhi(u.w);
  };

  for (int base = 0; base < deg; base += 64) {
    int i = base + lane;
    if (i < deg) {
      int s = csr_src[off + i];
      float l = a_src[s] + ad;
      l = l > 0.f ? l : 0.2f * l;
      meta[wv][lane] = make_int2(s, __float_as_int(__expf(l)));
    }
    int cnt = min(64, deg - base);
    int j = 0;
    for (; j + 16 <= cnt; j += 16) { proc(j + grp); proc(j + 8 + grp); }
    for (; j + 8 <= cnt; j += 8) proc(j + grp);
    int r = cnt - j;
    if (r > 0 && grp < r) proc(j + grp);
  }
#pragma unroll
  for (int k = 0; k < 8; ++k) {
    acc[k] += __shfl_xor(acc[k], 8);
    acc[k] += __shfl_xor(acc[k], 16);
    acc[k] += __shfl_xor(acc[k], 32);
  }
  den += __shfl_xor(den, 8);
  den += __shfl_xor(den, 16);
  den += __shfl_xor(den, 32);

  float inv = 1.f / (den + 1e-16f);
  float4 b01 = *(const float4*)(b2 + l3 * 8);
  float4 b23 = *(const float4*)(b2 + l3 * 8 + 4);
  float bb[8] = {b01.x, b01.y, b01.z, b01.w, b23.x, b23.y, b23.z, b23.w};
  float v[8];
#pragma unroll
  for (int k = 0; k < 8; ++k) v[k] = acc[k] * inv + bb[k];
  float m = v[0];
#pragma unroll
  for (int k = 1; k < 8; ++k) m = fmaxf(m, v[k]);
  m = fmaxf(m, __shfl_xor(m, 1));
  m = fmaxf(m, __shfl_xor(m, 2));
  m = fmaxf(m, __shfl_xor(m, 4));
  float sum = 0.f;
#pragma unroll
  for (int k = 0; k < 8; ++k) sum += __expf(v[k] - m);
  sum += __shfl_xor(sum, 1);
  sum += __shfl_xor(sum, 2);
  sum += __shfl_xor(sum, 4);
  float ls = m + logf(sum);
  if (lane < 8) {
    float4 o0 = make_float4(v[0] - ls, v[1] - ls, v[2] - ls, v[3] - ls);
    float4 o1 = make_float4(v[4] - ls, v[5] - ls, v[6] - ls, v[7] - ls);
    *(float4*)(out + (size_t)node * 64 + l3 * 8) = o0;
    *(float4*)(out + (size_t)node * 64 + l3 * 8 + 4) = o1;
  }
}

// ---------------- launch ----------------
extern "C" void kernel_launch(void* const* d_in, const int* in_sizes, int n_in,
                              void* d_out, int out_size, void* d_ws, size_t ws_size,
                              hipStream_t stream) {
  const float* x   = (const float*)d_in[0];
  const int*   ei  = (const int*)d_in[1];
  const float* W1  = (const float*)d_in[2];
  const float* as1 = (const float*)d_in[3];
  const float* ad1 = (const float*)d_in[4];
  const float* b1  = (const float*)d_in[5];
  const float* W2  = (const float*)d_in[6];
  const float* as2 = (const float*)d_in[7];
  const float* ad2 = (const float*)d_in[8];
  const float* b2  = (const float*)d_in[9];
  float* out = (float*)d_out;

  const int N  = in_sizes[0] / 256;
  const int E  = in_sizes[1] / 2;
  const int Et = E + N;
  const int N8 = (N + 7) / 8;
  const int nb  = (N + 255) / 256;
  const int nbt = (256 * 256 + 64 * 256 + 255) / 256;
  const int teamBlocks = 2048;

  char* p = (char*)d_ws;
  auto alloc = [&](size_t bytes) -> char* {
    char* r = p;
    p += (bytes + 255) & ~(size_t)255;
    return r;
  };
  unsigned char* H1b = (unsigned char*)alloc((size_t)N * 256);  // fp8 e4m3
  u16* h1act   = (u16*)alloc((size_t)N * 256 * 2);
  u16* H2b     = (u16*)alloc((size_t)N * 64 * 2);
  u16* W1T     = (u16*)alloc((size_t)256 * 256 * 2);
  u16* W2T     = (u16*)alloc((size_t)64 * 256 * 2);
  float* a_src1 = (float*)alloc((size_t)N * 2 * 4);
  float* a_dst1 = (float*)alloc((size_t)N * 2 * 4);
  float* a_src2 = (float*)alloc((size_t)N * 4);
  float* a_dst2 = (float*)alloc((size_t)N * 4);
  int* counts   = (int*)alloc((size_t)N * 4);
  int* offsets  = (int*)alloc((size_t)(N + 1) * 4);
  int* cursor   = (int*)alloc((size_t)N * 4);
  int* bsums    = (int*)alloc((size_t)1024 * 4);
  int* csr_src  = (int*)alloc((size_t)Et * 4);

  const int tb = 256;

  // CSR build
  hipMemsetAsync(counts, 0, (size_t)N * 4, stream);
  prep_kernel<<<teamBlocks + nbt, tb, 0, stream>>>(ei, E, N, N8, counts, W1, W2, W1T, W2T,
                                                   teamBlocks);
  block_scan_kernel<<<nb, tb, 0, stream>>>(counts, offsets, bsums, N);
  scan_sums_kernel<<<1, 1024, 0, stream>>>(bsums, offsets, nb, N);
  add_base_kernel<<<nb, tb, 0, stream>>>(offsets, cursor, bsums, N);
  scatter_kernel<<<teamBlocks, tb, 0, stream>>>(ei, E, N, N8, cursor, csr_src, teamBlocks);

  // layer 1: gemm 64x128 tiles (grid.y = head), fused a1, fp8 C
  dim3 g1((N + 63) / 64, 2);
  mfma_gemm<64, 128, 32, 32, 64, true, 1><<<g1, tb, 0, stream>>>(
      x, W1T, (u16*)H1b, as1, ad1, a_src1, a_dst1, N, 256, 256);
  agg1_kernel<<<(N + 3) / 4, tb, 0, stream>>>(H1b, offsets, csr_src, a_src1, a_dst1, b1,
                                              h1act, N);

  // layer 2: gemm + fused a2
  mfma_gemm<128, 64, 32, 32, 64, false, 2><<<(N + 127) / 128, tb, 0, stream>>>(
      h1act, W2T, H2b, as2, ad2, a_src2, a_dst2, N, 256, 64);
  agg2_kernel<<<(N + 3) / 4, tb, 0, stream>>>(H2b, offsets, csr_src, a_src2, a_dst2, b2,
                                              out, N);
}

// Round 15
// 197.454 us; speedup vs baseline: 1.6171x; 1.0017x over previous
//
#include <hip/hip_runtime.h>
#include <hip/hip_bf16.h>

typedef unsigned short u16;
typedef short bf8_t __attribute__((ext_vector_type(8)));
typedef float f32x4 __attribute__((ext_vector_type(4)));
typedef float f32x2 __attribute__((ext_vector_type(2)));

__device__ inline u16 f2bf(float f) {
  unsigned u = __float_as_uint(f);
  u += 0x7FFFu + ((u >> 16) & 1u);
  return (u16)(u >> 16);
}
__device__ inline float bf2f(u16 h) { return __uint_as_float(((unsigned)h) << 16); }
__device__ inline float bflo(unsigned u) { return __uint_as_float(u << 16); }
__device__ inline float bfhi(unsigned u) { return __uint_as_float(u & 0xffff0000u); }

// ---------------- zero counts (replaces 42us runtime fillBuffer) ----------------
__global__ void zero_kernel(int4* __restrict__ p, int n4) {
  int i = blockIdx.x * 256 + threadIdx.x;
  if (i < n4) p[i] = make_int4(0, 0, 0, 0);
}

// ---------------- count (XCD-team filtered) + weight transposes ----------------
__global__ void prep_kernel(const int* __restrict__ ei, int E, int N, int N8,
                            int* __restrict__ counts,
                            const float* __restrict__ W1, const float* __restrict__ W2,
                            u16* __restrict__ W1T, u16* __restrict__ W2T, int teamBlocks) {
  if ((int)blockIdx.x < teamBlocks) {
    const int team = blockIdx.x & 7;
    const int tslot = blockIdx.x >> 3;
    const int TB = teamBlocks >> 3;
    const int lo = team * N8, hi = min(N, lo + N8);
    const int Et = E + N;
    for (int e = tslot * 256 + (int)threadIdx.x; e < Et; e += TB * 256) {
      int d = (e < E) ? ei[E + e] : (e - E);
      if (d >= lo && d < hi) atomicAdd(&counts[d], 1);
    }
  } else {
    int idx = ((int)blockIdx.x - teamBlocks) * 256 + (int)threadIdx.x;
    if (idx < 256 * 256) {
      int m = idx >> 8, k = idx & 255;
      W1T[idx] = f2bf(W1[k * 256 + m]);
    } else if (idx < 256 * 256 + 64 * 256) {
      int i = idx - 256 * 256;
      int m = i >> 8, k = i & 255;
      W2T[i] = f2bf(W2[k * 64 + m]);
    }
  }
}

// ---------------- hierarchical scan ----------------
__global__ void block_scan_kernel(const int* __restrict__ counts, int* __restrict__ offsets,
                                  int* __restrict__ bsums, int N) {
  __shared__ int sm[256];
  int tid = threadIdx.x;
  int gid = blockIdx.x * 256 + tid;
  int v = (gid < N) ? counts[gid] : 0;
  int val = v;
  sm[tid] = val;
  __syncthreads();
  for (int off = 1; off < 256; off <<= 1) {
    int o = (tid >= off) ? sm[tid - off] : 0;
    __syncthreads();
    val += o;
    sm[tid] = val;
    __syncthreads();
  }
  if (gid < N) offsets[gid] = val - v;
  if (tid == 255) bsums[blockIdx.x] = val;
}

__global__ void scan_sums_kernel(int* __restrict__ bsums, int* __restrict__ offsets,
                                 int nb, int N) {
  __shared__ int sm[1024];
  int tid = threadIdx.x;
  int v = (tid < nb) ? bsums[tid] : 0;
  int val = v;
  sm[tid] = val;
  __syncthreads();
  for (int off = 1; off < 1024; off <<= 1) {
    int o = (tid >= off) ? sm[tid - off] : 0;
    __syncthreads();
    val += o;
    sm[tid] = val;
    __syncthreads();
  }
  if (tid < nb) bsums[tid] = val - v;
  if (tid == 1023) offsets[N] = val;
}

__global__ void add_base_kernel(int* __restrict__ offsets, int* __restrict__ cursor,
                                const int* __restrict__ bsums, int N) {
  int gid = blockIdx.x * 256 + threadIdx.x;
  if (gid >= N) return;
  int o = offsets[gid] + bsums[blockIdx.x];
  offsets[gid] = o;
  cursor[gid] = o;
}

// ---------------- scatter (XCD-team filtered) ----------------
__global__ void scatter_kernel(const int* __restrict__ ei, int E, int N, int N8,
                               int* __restrict__ cursor, int* __restrict__ csr_src,
                               int teamBlocks) {
  const int team = blockIdx.x & 7;
  const int tslot = blockIdx.x >> 3;
  const int TB = teamBlocks >> 3;
  const int lo = team * N8, hi = min(N, lo + N8);
  const int Et = E + N;
  for (int e = tslot * 256 + (int)threadIdx.x; e < Et; e += TB * 256) {
    int d = (e < E) ? ei[E + e] : (e - E);
    if (d >= lo && d < hi) {
      int s = (e < E) ? ei[e] : d;
      int pos = atomicAdd(&cursor[d], 1);
      csr_src[pos] = s;
    }
  }
}

// ---------------- MFMA GEMM: C[N][Mtot] tile (BM x BN) at (blockIdx.x, blockIdx.y) ----------------
// EPI 1: layer1 — C written fp8 e4m3; block y covers one head (BN=128); 2x2 wave grid.
// EPI 2: layer2 — C written bf16; 1 head in-wave epilogue.
template<int BM, int BN, int BK, int WM, int WN, bool AF32, int EPI>
__global__ __launch_bounds__(256) void mfma_gemm(const void* __restrict__ Ap,
                                                 const u16* __restrict__ Bt,
                                                 u16* __restrict__ C,
                                                 const float* __restrict__ att_s,
                                                 const float* __restrict__ att_d,
                                                 float* __restrict__ a_s,
                                                 float* __restrict__ a_d,
                                                 int N, int K, int Mtot) {
  constexpr int PAD = 8;
  __shared__ u16 As[BM][BK + PAD];
  __shared__ u16 Bs[BN][BK + PAD];
  const int tid = threadIdx.x;
  const int row0 = blockIdx.x * BM;
  const int col0 = blockIdx.y * BN;
  const int w = tid >> 6, lane = tid & 63;
  const int wr = (w / (BN / WN)) * WM;
  const int wc = (w % (BN / WN)) * WN;
  constexpr int MF = WM / 16, NF = WN / 16;
  constexpr int CPR = BK / 8;
  f32x4 acc[MF][NF] = {};

  for (int k0 = 0; k0 < K; k0 += BK) {
    constexpr int ACH = BM * CPR;
#pragma unroll
    for (int c = 0; c < ACH; c += 256) {
      int cc = c + tid;
      int r = cc / CPR, kc = cc % CPR;
      int row = row0 + r;
      if (AF32) {
        const float* A = (const float*)Ap;
        float4 v0 = make_float4(0.f, 0.f, 0.f, 0.f), v1 = v0;
        if (row < N) {
          const float* p = A + (size_t)row * K + k0 + kc * 8;
          v0 = *(const float4*)p;
          v1 = *(const float4*)(p + 4);
        }
        union { __hip_bfloat162 h[4]; uint4 u; } cv;
        cv.h[0] = __float22bfloat162_rn(make_float2(v0.x, v0.y));
        cv.h[1] = __float22bfloat162_rn(make_float2(v0.z, v0.w));
        cv.h[2] = __float22bfloat162_rn(make_float2(v1.x, v1.y));
        cv.h[3] = __float22bfloat162_rn(make_float2(v1.z, v1.w));
        *(uint4*)&As[r][kc * 8] = cv.u;
      } else {
        const u16* A = (const u16*)Ap;
        uint4 v = make_uint4(0, 0, 0, 0);
        if (row < N) v = *(const uint4*)(A + (size_t)row * K + k0 + kc * 8);
        *(uint4*)&As[r][kc * 8] = v;
      }
    }
    constexpr int BCH = BN * CPR;
#pragma unroll
    for (int c = 0; c < BCH; c += 256) {
      int cc = c + tid;
      int r = cc / CPR, kc = cc % CPR;
      *(uint4*)&Bs[r][kc * 8] = *(const uint4*)(Bt + (size_t)(col0 + r) * K + k0 + kc * 8);
    }
    __syncthreads();
    const int lr = lane & 15, lk = (lane >> 4) * 8;
    bf8_t a[MF], b[NF];
#pragma unroll
    for (int mi = 0; mi < MF; ++mi) a[mi] = *(bf8_t*)&As[wr + mi * 16 + lr][lk];
#pragma unroll
    for (int ni = 0; ni < NF; ++ni) b[ni] = *(bf8_t*)&Bs[wc + ni * 16 + lr][lk];
#pragma unroll
    for (int mi = 0; mi < MF; ++mi)
#pragma unroll
      for (int ni = 0; ni < NF; ++ni)
        acc[mi][ni] = __builtin_amdgcn_mfma_f32_16x16x32_bf16(a[mi], b[ni], acc[mi][ni], 0, 0, 0);
    __syncthreads();
  }
  // C-write: col=lane&15, row=(lane>>4)*4+reg
  unsigned char* C8 = (unsigned char*)C;
#pragma unroll
  for (int mi = 0; mi < MF; ++mi)
#pragma unroll
    for (int ni = 0; ni < NF; ++ni)
#pragma unroll
      for (int r = 0; r < 4; ++r) {
        int row = row0 + wr + mi * 16 + (lane >> 4) * 4 + r;
        int col = col0 + wc + ni * 16 + (lane & 15);
        if (row < N) {
          if (EPI == 1) {
            int p8 = __builtin_amdgcn_cvt_pk_fp8_f32(acc[mi][ni][r], acc[mi][ni][r], 0, false);
            C8[(size_t)row * Mtot + col] = (unsigned char)(p8 & 0xff);
          } else {
            C[(size_t)row * Mtot + col] = f2bf(acc[mi][ni][r]);
          }
        }
      }

  // ---- fused attention-scalar epilogue ----
  if (EPI == 1) {
    __shared__ float sm_s[4][64];
    __shared__ float sm_d[4][64];
    float asl[NF], adl[NF];
#pragma unroll
    for (int ni = 0; ni < NF; ++ni) {
      asl[ni] = att_s[col0 + wc + ni * 16 + (lane & 15)];
      adl[ni] = att_d[col0 + wc + ni * 16 + (lane & 15)];
    }
#pragma unroll
    for (int mi = 0; mi < MF; ++mi)
#pragma unroll
      for (int r = 0; r < 4; ++r) {
        float ps = 0.f, pd = 0.f;
#pragma unroll
        for (int ni = 0; ni < NF; ++ni) {
          float c = acc[mi][ni][r];
          ps += c * asl[ni];
          pd += c * adl[ni];
        }
#pragma unroll
        for (int o = 1; o < 16; o <<= 1) {
          ps += __shfl_xor(ps, o);
          pd += __shfl_xor(pd, o);
        }
        if ((lane & 15) == 0) {
          int row = wr + mi * 16 + (lane >> 4) * 4 + r;
          sm_s[w][row] = ps;
          sm_d[w][row] = pd;
        }
      }
    __syncthreads();
    if (tid < 64) {
      int row = tid;
      int base = (row >> 5) * 2;
      int grow = row0 + row;
      if (grow < N) {
        a_s[grow * 2 + blockIdx.y] = sm_s[base][row] + sm_s[base + 1][row];
        a_d[grow * 2 + blockIdx.y] = sm_d[base][row] + sm_d[base + 1][row];
      }
    }
  } else if (EPI == 2) {
    float asl[NF], adl[NF];
#pragma unroll
    for (int ni = 0; ni < NF; ++ni) {
      asl[ni] = att_s[ni * 16 + (lane & 15)];
      adl[ni] = att_d[ni * 16 + (lane & 15)];
    }
#pragma unroll
    for (int mi = 0; mi < MF; ++mi)
#pragma unroll
      for (int r = 0; r < 4; ++r) {
        float ps = 0.f, pd = 0.f;
#pragma unroll
        for (int ni = 0; ni < NF; ++ni) {
          float c = acc[mi][ni][r];
          ps += c * asl[ni];
          pd += c * adl[ni];
        }
#pragma unroll
        for (int o = 1; o < 16; o <<= 1) {
          ps += __shfl_xor(ps, o);
          pd += __shfl_xor(pd, o);
        }
        int row = row0 + wr + mi * 16 + (lane >> 4) * 4 + r;
        if ((lane & 15) == 0 && row < N) {
          a_s[row] = ps;
          a_d[row] = pd;
        }
      }
  }
}

// ---------------- layer-1 aggregation: fp8 gather (4B/lane = 4ch), 4x unroll ----------------
__global__ void agg1_kernel(const unsigned char* __restrict__ H1, const int* __restrict__ offsets,
                            const int* __restrict__ csr_src,
                            const float* __restrict__ a_src, const float* __restrict__ a_dst,
                            const float* __restrict__ b1, u16* __restrict__ out, int N) {
  __shared__ int4 meta[4][64];
  int wv = threadIdx.x >> 6;
  int lane = threadIdx.x & 63;
  int node = blockIdx.x * 4 + wv;
  if (node >= N) return;
  int off = offsets[node];
  int deg = offsets[node + 1] - off;
  float ad0 = a_dst[node * 2 + 0];
  float ad1 = a_dst[node * 2 + 1];
  bool hi = lane >= 32;
  const unsigned loff = (unsigned)(lane * 4);
  float4 acc = make_float4(0.f, 0.f, 0.f, 0.f);
  float den = 0.f;
  const int4* mw = meta[wv];

  auto proc = [&](int4 m) {
    float w = hi ? __int_as_float(m.z) : __int_as_float(m.y);
    unsigned u = *(const unsigned*)(H1 + (((unsigned)m.x << 8) + loff));
    f32x2 lo2 = __builtin_amdgcn_cvt_pk_f32_fp8(u, false);
    f32x2 hi2 = __builtin_amdgcn_cvt_pk_f32_fp8(u, true);
    den += w;
    acc.x += w * lo2.x;
    acc.y += w * lo2.y;
    acc.z += w * hi2.x;
    acc.w += w * hi2.y;
  };

  for (int base = 0; base < deg; base += 64) {
    int i = base + lane;
    if (i < deg) {
      int s = csr_src[off + i];
      float l0 = a_src[s * 2 + 0] + ad0;
      float l1 = a_src[s * 2 + 1] + ad1;
      l0 = l0 > 0.f ? l0 : 0.2f * l0;
      l1 = l1 > 0.f ? l1 : 0.2f * l1;
      meta[wv][lane] = make_int4(s, __float_as_int(__expf(l0)), __float_as_int(__expf(l1)), 0);
    }
    int cnt = min(64, deg - base);
    int j = 0;
    for (; j + 4 <= cnt; j += 4) {
      int4 m0 = mw[j], m1 = mw[j + 1], m2 = mw[j + 2], m3 = mw[j + 3];
      proc(m0); proc(m1); proc(m2); proc(m3);
    }
    for (; j < cnt; ++j) proc(mw[j]);
  }
  float inv = 1.f / (den + 1e-16f);
  float4 bb = *(const float4*)(b1 + lane * 4);
  float o0 = acc.x * inv + bb.x;
  float o1 = acc.y * inv + bb.y;
  float o2 = acc.z * inv + bb.z;
  float o3 = acc.w * inv + bb.w;
  o0 = o0 > 0.f ? o0 : expm1f(o0);
  o1 = o1 > 0.f ? o1 : expm1f(o1);
  o2 = o2 > 0.f ? o2 : expm1f(o2);
  o3 = o3 > 0.f ? o3 : expm1f(o3);
  uint2 ov;
  ov.x = (unsigned)f2bf(o0) | ((unsigned)f2bf(o1) << 16);
  ov.y = (unsigned)f2bf(o2) | ((unsigned)f2bf(o3) << 16);
  *(uint2*)(out + (size_t)node * 256 + lane * 4) = ov;
}

// ---------------- layer-2 aggregation: 8 edges/wave-step + log_softmax ----------------
__global__ void agg2_kernel(const u16* __restrict__ H2, const int* __restrict__ offsets,
                            const int* __restrict__ csr_src,
                            const float* __restrict__ a_src, const float* __restrict__ a_dst,
                            const float* __restrict__ b2, float* __restrict__ out, int N) {
  __shared__ int2 meta[4][64];
  int wv = threadIdx.x >> 6;
  int lane = threadIdx.x & 63;
  int node = blockIdx.x * 4 + wv;
  if (node >= N) return;
  int off = offsets[node];
  int deg = offsets[node + 1] - off;
  float ad = a_dst[node];
  const int grp = lane >> 3;
  const int l3 = lane & 7;
  const char* H2c = (const char*)H2;
  const unsigned loff = (unsigned)(l3 * 16);
  float acc[8] = {0.f, 0.f, 0.f, 0.f, 0.f, 0.f, 0.f, 0.f};
  float den = 0.f;
  const int2* mw = meta[wv];

  auto proc = [&](int jj) {
    int2 m = mw[jj];
    float w = __int_as_float(m.y);
    uint4 u = *(const uint4*)(H2c + (((unsigned)m.x << 7) + loff));
    den += w;
    acc[0] += w * bflo(u.x); acc[1] += w * bfhi(u.x);
    acc[2] += w * bflo(u.y); acc[3] += w * bfhi(u.y);
    acc[4] += w * bflo(u.z); acc[5] += w * bfhi(u.z);
    acc[6] += w * bflo(u.w); acc[7] += w * bfhi(u.w);
  };

  for (int base = 0; base < deg; base += 64) {
    int i = base + lane;
    if (i < deg) {
      int s = csr_src[off + i];
      float l = a_src[s] + ad;
      l = l > 0.f ? l : 0.2f * l;
      meta[wv][lane] = make_int2(s, __float_as_int(__expf(l)));
    }
    int cnt = min(64, deg - base);
    int j = 0;
    for (; j + 16 <= cnt; j += 16) { proc(j + grp); proc(j + 8 + grp); }
    for (; j + 8 <= cnt; j += 8) proc(j + grp);
    int r = cnt - j;
    if (r > 0 && grp < r) proc(j + grp);
  }
#pragma unroll
  for (int k = 0; k < 8; ++k) {
    acc[k] += __shfl_xor(acc[k], 8);
    acc[k] += __shfl_xor(acc[k], 16);
    acc[k] += __shfl_xor(acc[k], 32);
  }
  den += __shfl_xor(den, 8);
  den += __shfl_xor(den, 16);
  den += __shfl_xor(den, 32);

  float inv = 1.f / (den + 1e-16f);
  float4 b01 = *(const float4*)(b2 + l3 * 8);
  float4 b23 = *(const float4*)(b2 + l3 * 8 + 4);
  float bb[8] = {b01.x, b01.y, b01.z, b01.w, b23.x, b23.y, b23.z, b23.w};
  float v[8];
#pragma unroll
  for (int k = 0; k < 8; ++k) v[k] = acc[k] * inv + bb[k];
  float m = v[0];
#pragma unroll
  for (int k = 1; k < 8; ++k) m = fmaxf(m, v[k]);
  m = fmaxf(m, __shfl_xor(m, 1));
  m = fmaxf(m, __shfl_xor(m, 2));
  m = fmaxf(m, __shfl_xor(m, 4));
  float sum = 0.f;
#pragma unroll
  for (int k = 0; k < 8; ++k) sum += __expf(v[k] - m);
  sum += __shfl_xor(sum, 1);
  sum += __shfl_xor(sum, 2);
  sum += __shfl_xor(sum, 4);
  float ls = m + logf(sum);
  if (lane < 8) {
    float4 o0 = make_float4(v[0] - ls, v[1] - ls, v[2] - ls, v[3] - ls);
    float4 o1 = make_float4(v[4] - ls, v[5] - ls, v[6] - ls, v[7] - ls);
    *(float4*)(out + (size_t)node * 64 + l3 * 8) = o0;
    *(float4*)(out + (size_t)node * 64 + l3 * 8 + 4) = o1;
  }
}

// ---------------- launch ----------------
extern "C" void kernel_launch(void* const* d_in, const int* in_sizes, int n_in,
                              void* d_out, int out_size, void* d_ws, size_t ws_size,
                              hipStream_t stream) {
  const float* x   = (const float*)d_in[0];
  const int*   ei  = (const int*)d_in[1];
  const float* W1  = (const float*)d_in[2];
  const float* as1 = (const float*)d_in[3];
  const float* ad1 = (const float*)d_in[4];
  const float* b1  = (const float*)d_in[5];
  const float* W2  = (const float*)d_in[6];
  const float* as2 = (const float*)d_in[7];
  const float* ad2 = (const float*)d_in[8];
  const float* b2  = (const float*)d_in[9];
  float* out = (float*)d_out;

  const int N  = in_sizes[0] / 256;
  const int E  = in_sizes[1] / 2;
  const int Et = E + N;
  const int N8 = (N + 7) / 8;
  const int nb  = (N + 255) / 256;
  const int nbt = (256 * 256 + 64 * 256 + 255) / 256;
  const int teamBlocks = 2048;

  char* p = (char*)d_ws;
  auto alloc = [&](size_t bytes) -> char* {
    char* r = p;
    p += (bytes + 255) & ~(size_t)255;
    return r;
  };
  unsigned char* H1b = (unsigned char*)alloc((size_t)N * 256);  // fp8 e4m3
  u16* h1act   = (u16*)alloc((size_t)N * 256 * 2);
  u16* H2b     = (u16*)alloc((size_t)N * 64 * 2);
  u16* W1T     = (u16*)alloc((size_t)256 * 256 * 2);
  u16* W2T     = (u16*)alloc((size_t)64 * 256 * 2);
  float* a_src1 = (float*)alloc((size_t)N * 2 * 4);
  float* a_dst1 = (float*)alloc((size_t)N * 2 * 4);
  float* a_src2 = (float*)alloc((size_t)N * 4);
  float* a_dst2 = (float*)alloc((size_t)N * 4);
  int* counts   = (int*)alloc((size_t)(N + 4) * 4);
  int* offsets  = (int*)alloc((size_t)(N + 1) * 4);
  int* cursor   = (int*)alloc((size_t)N * 4);
  int* bsums    = (int*)alloc((size_t)1024 * 4);
  int* csr_src  = (int*)alloc((size_t)Et * 4);

  const int tb = 256;
  const int n4 = (N + 3) / 4;  // int4 count for zeroing counts

  // CSR build
  zero_kernel<<<(n4 + tb - 1) / tb, tb, 0, stream>>>((int4*)counts, n4);
  prep_kernel<<<teamBlocks + nbt, tb, 0, stream>>>(ei, E, N, N8, counts, W1, W2, W1T, W2T,
                                                   teamBlocks);
  block_scan_kernel<<<nb, tb, 0, stream>>>(counts, offsets, bsums, N);
  scan_sums_kernel<<<1, 1024, 0, stream>>>(bsums, offsets, nb, N);
  add_base_kernel<<<nb, tb, 0, stream>>>(offsets, cursor, bsums, N);
  scatter_kernel<<<teamBlocks, tb, 0, stream>>>(ei, E, N, N8, cursor, csr_src, teamBlocks);

  // layer 1: gemm 64x128 tiles (grid.y = head), fused a1, fp8 C
  dim3 g1((N + 63) / 64, 2);
  mfma_gemm<64, 128, 32, 32, 64, true, 1><<<g1, tb, 0, stream>>>(
      x, W1T, (u16*)H1b, as1, ad1, a_src1, a_dst1, N, 256, 256);
  agg1_kernel<<<(N + 3) / 4, tb, 0, stream>>>(H1b, offsets, csr_src, a_src1, a_dst1, b1,
                                              h1act, N);

  // layer 2: gemm + fused a2
  mfma_gemm<128, 64, 32, 32, 64, false, 2><<<(N + 127) / 128, tb, 0, stream>>>(
      h1act, W2T, H2b, as2, ad2, a_src2, a_dst2, N, 256, 64);
  agg2_kernel<<<(N + 3) / 4, tb, 0, stream>>>(H2b, offsets, csr_src, a_src2, a_dst2, b2,
                                              out, N);
}